// Round 1
// baseline (1244.155 us; speedup 1.0000x reference)
//
#include <hip/hip_runtime.h>
#include <cstdint>
#include <cstddef>

// ============================================================================
// MildAugmentStage: random-resized-crop (cubic, antialias) + color jitter +
// separable gaussian blur, reproducing jax.random (threefry2x32) exactly.
// ============================================================================

#define JAX_PARTITIONABLE 1   // JAX >= 0.4.30 default. Flip to 0 if absmax ~O(1).

#define NB 256
#define NC 3
#define IH 256
#define IW 256
#define OS 224
#define PIX (OS * OS)         // 50176
#define PSTRIDE 32            // floats per batch param slot
#define MAXTAP 6

// param slot layout (floats):
// 0 inv_sy, 1 tiy, 2 ksy, 3 inv_sx, 4 tix, 5 ksx,
// 6 bf, 7 cf, 8 sf, 9 hf, 10 cj, 11 bl, 12..26 kern[15]

// ---------------- threefry-2x32 (JAX rotation/key schedule) ----------------
__device__ __forceinline__ void tf2x32(uint32_t k0, uint32_t k1,
                                       uint32_t x0, uint32_t x1,
                                       uint32_t& o0, uint32_t& o1) {
  uint32_t ks[3] = {k0, k1, k0 ^ k1 ^ 0x1BD11BDAu};
  uint32_t a = x0 + ks[0], b = x1 + ks[1];
  const int R[2][4] = {{13, 15, 26, 6}, {17, 29, 16, 24}};
  #pragma unroll
  for (int i = 0; i < 5; ++i) {
    #pragma unroll
    for (int j = 0; j < 4; ++j) {
      int r = R[i & 1][j];
      a += b;
      b = (b << r) | (b >> (32 - r));
      b ^= a;
    }
    a += ks[(i + 1) % 3];
    b += ks[(i + 2) % 3] + (uint32_t)(i + 1);
  }
  o0 = a; o1 = b;
}

__device__ __forceinline__ float bits_to_u01(uint32_t bits) {
  uint32_t fb = (bits >> 9) | 0x3f800000u;
  return __uint_as_float(fb) - 1.0f;
}

// uniform [0,1) sample i of an N-element draw (N even)
__device__ __forceinline__ float u01_n(uint32_t k0, uint32_t k1, uint32_t i, uint32_t N) {
#if JAX_PARTITIONABLE
  uint32_t a, b; tf2x32(k0, k1, 0u, i, a, b);
  return bits_to_u01(a ^ b);
#else
  uint32_t half = N >> 1;
  uint32_t a, b;
  if (i < half) { tf2x32(k0, k1, i, half + i, a, b); return bits_to_u01(a); }
  tf2x32(k0, k1, i - half, i, a, b); return bits_to_u01(b);
#endif
}

// jax.random.uniform: max(mn, u*(mx-mn)+mn), unfused f32 mul/add like XLA
__device__ __forceinline__ float junif(uint32_t k0, uint32_t k1, uint32_t i, uint32_t N,
                                       float mn, float mx) {
  float u = u01_n(k0, k1, i, N);
  float d = __fsub_rn(mx, mn);
  float r = __fadd_rn(__fmul_rn(u, d), mn);
  return fmaxf(mn, r);
}

// ---------------- per-batch augmentation parameters ----------------
__global__ __launch_bounds__(256) void k_params(float* __restrict__ prm) {
  int b = threadIdx.x;
  if (b >= NB) return;
  uint32_t ks[10][2];
#if JAX_PARTITIONABLE
  for (int j = 0; j < 10; ++j) tf2x32(0u, 42u, 0u, (uint32_t)j, ks[j][0], ks[j][1]);
#else
  {
    uint32_t flat[20];
    for (int j = 0; j < 10; ++j) {
      uint32_t a, bb; tf2x32(0u, 42u, (uint32_t)j, (uint32_t)(10 + j), a, bb);
      flat[j] = a; flat[10 + j] = bb;
    }
    for (int j = 0; j < 10; ++j) { ks[j][0] = flat[2 * j]; ks[j][1] = flat[2 * j + 1]; }
  }
#endif
  float* P = prm + b * PSTRIDE;

  float uarea = junif(ks[0][0], ks[0][1], b, NB, 0.8f, 1.0f);
  float area  = __fmul_rn(65536.0f, uarea);
  float lmn = (float)(-0.28768207245178085);  // log(3/4) as f32
  float lmx = (float)( 0.28768207245178085);  // log(4/3) as f32
  float ur  = junif(ks[1][0], ks[1][1], b, NB, lmn, lmx);
  float ratio = (float)exp((double)ur);       // ~correctly-rounded expf

  float cw = rintf(__fsqrt_rn(__fmul_rn(area, ratio)));
  cw = fminf(fmaxf(cw, 1.0f), 256.0f);
  float ch = rintf(__fsqrt_rn(__fdiv_rn(area, ratio)));
  ch = fminf(fmaxf(ch, 1.0f), 256.0f);

  float ui = u01_n(ks[2][0], ks[2][1], b, NB);
  float uj = u01_n(ks[3][0], ks[3][1], b, NB);
  float i0 = floorf(__fmul_rn(ui, __fadd_rn(__fsub_rn(256.0f, ch), 1.0f)));
  float j0 = floorf(__fmul_rn(uj, __fadd_rn(__fsub_rn(256.0f, cw), 1.0f)));

  float sy = __fdiv_rn(224.0f, ch), sx = __fdiv_rn(224.0f, cw);
  float ty = -__fmul_rn(i0, sy),   tx = -__fmul_rn(j0, sx);
  float inv_sy = __fdiv_rn(1.0f, sy), inv_sx = __fdiv_rn(1.0f, sx);
  P[0] = inv_sy;
  P[1] = __fmul_rn(ty, inv_sy);   // translation * inv_scale (exactly as JAX)
  P[2] = fmaxf(inv_sy, 1.0f);     // antialias kernel_scale
  P[3] = inv_sx;
  P[4] = __fmul_rn(tx, inv_sx);
  P[5] = fmaxf(inv_sx, 1.0f);

  P[6] = junif(ks[4][0], ks[4][1], b, NB, 0.9f, 1.1f);     // brightness
  P[7] = junif(ks[5][0], ks[5][1], b, NB, 0.9f, 1.1f);     // contrast
  P[8] = junif(ks[6][0], ks[6][1], b, NB, 0.9f, 1.1f);     // saturation
  P[9] = junif(ks[7][0], ks[7][1], b, NB, -0.01f, 0.01f);  // hue
  P[10] = (u01_n(ks[8][0], ks[8][1], b, NB) < 0.8f) ? 1.0f : 0.0f;

  uint32_t kb0[2], kb1[2];
#if JAX_PARTITIONABLE
  tf2x32(ks[9][0], ks[9][1], 0u, 0u, kb0[0], kb0[1]);
  tf2x32(ks[9][0], ks[9][1], 0u, 1u, kb1[0], kb1[1]);
#else
  {
    uint32_t f0, s0, f1, s1;
    tf2x32(ks[9][0], ks[9][1], 0u, 2u, f0, s0);
    tf2x32(ks[9][0], ks[9][1], 1u, 3u, f1, s1);
    kb0[0] = f0; kb0[1] = f1; kb1[0] = s0; kb1[1] = s1;
  }
#endif
  float sg = junif(kb0[0], kb0[1], b, NB, 0.1f, 2.0f);
  P[11] = (u01_n(kb1[0], kb1[1], b, NB) < 0.5f) ? 1.0f : 0.0f;

  float e[15]; float ssum = 0.0f;
  for (int k = 0; k < 15; ++k) {
    float t = (float)k - 7.0f;
    float z = t / sg;
    e[k] = expf(-0.5f * (z * z));
    ssum += e[k];
  }
  for (int k = 0; k < 15; ++k) P[12 + k] = e[k] / ssum;
}

// ---------------- cubic (Keys, a=-0.5) resize ----------------
__device__ __forceinline__ float keys_cubic(float x) {
  float o = ((1.5f * x - 2.5f) * x) * x + 1.0f;
  if (x >= 1.0f) o = ((-0.5f * x + 2.5f) * x - 4.0f) * x + 2.0f;
  if (x >= 2.0f) o = 0.0f;
  return o;
}

// one block per (b, c, oy) output row
__global__ __launch_bounds__(256) void k_resize(const float* __restrict__ x,
                                                float* __restrict__ xc,
                                                float* __restrict__ rowsum,
                                                const float* __restrict__ prm) {
  int blk = blockIdx.x;
  int oy = blk % OS;
  int bc = blk / OS;
  int c = bc % NC, b = bc / NC;
  const float* P = prm + b * PSTRIDE;
  float inv_sy = P[0], tiy = P[1], ksy = P[2];
  float inv_sx = P[3], tix = P[4], ksx = P[5], bfac = P[6];

  float sfy = ((float)oy + 0.5f) * inv_sy - tiy - 0.5f;
  float ry = 2.0f * ksy;
  int iy0 = max(0, (int)ceilf(sfy - ry));
  int iy1 = min(IH - 1, (int)floorf(sfy + ry));
  int ny = iy1 - iy0 + 1;
  if (ny > MAXTAP) ny = MAXTAP;
  float wy[MAXTAP]; float toty = 0.0f;
  for (int j = 0; j < ny; ++j) {
    float d = fabsf(sfy - (float)(iy0 + j)) / ksy;
    wy[j] = keys_cubic(d);
    toty += wy[j];
  }
  if (fabsf(toty) > 1.1920929e-4f) { for (int j = 0; j < ny; ++j) wy[j] /= toty; }
  else                             { for (int j = 0; j < ny; ++j) wy[j] = 0.0f; }

  __shared__ float tile[MAXTAP][IW];
  int t = threadIdx.x;
  const float* src = x + (size_t)(b * NC + c) * IH * IW;
  for (int j = 0; j < ny; ++j) tile[j][t] = src[(size_t)(iy0 + j) * IW + t];
  __syncthreads();

  float res = 0.0f;
  if (t < OS) {
    float sfx = ((float)t + 0.5f) * inv_sx - tix - 0.5f;
    float rx = 2.0f * ksx;
    int ix0 = max(0, (int)ceilf(sfx - rx));
    int ix1 = min(IW - 1, (int)floorf(sfx + rx));
    int nx = ix1 - ix0 + 1;
    if (nx > MAXTAP) nx = MAXTAP;
    float wx[MAXTAP]; float totx = 0.0f;
    for (int j = 0; j < nx; ++j) {
      float d = fabsf(sfx - (float)(ix0 + j)) / ksx;
      wx[j] = keys_cubic(d);
      totx += wx[j];
    }
    if (fabsf(totx) > 1.1920929e-4f) { for (int j = 0; j < nx; ++j) wx[j] /= totx; }
    else                             { for (int j = 0; j < nx; ++j) wx[j] = 0.0f; }
    for (int jy = 0; jy < ny; ++jy) {
      float acc = 0.0f;
      for (int jx = 0; jx < nx; ++jx) acc += wx[jx] * tile[jy][ix0 + jx];
      res += wy[jy] * acc;
    }
    xc[((size_t)(b * NC + c) * OS + oy) * OS + t] = res;
  }

  // partial row sum of clip(xc*bf) for mean_gray (contrast term)
  float v = (t < OS) ? fminf(fmaxf(res * bfac, 0.0f), 1.0f) : 0.0f;
  for (int off = 32; off > 0; off >>= 1) v += __shfl_down(v, off, 64);
  __shared__ float wsum[4];
  int wid = t >> 6, lane = t & 63;
  if (lane == 0) wsum[wid] = v;
  __syncthreads();
  if (t == 0) rowsum[blk] = wsum[0] + wsum[1] + wsum[2] + wsum[3];
}

__global__ __launch_bounds__(256) void k_means(const float* __restrict__ rowsum,
                                               float* __restrict__ means) {
  int b = blockIdx.x, t = threadIdx.x;
  float acc = 0.0f;
  for (int i = t; i < NC * OS; i += 256) {
    int c = i / OS, yy = i - c * OS;
    float w = (c == 0) ? 0.2989f : ((c == 1) ? 0.587f : 0.114f);
    acc += w * rowsum[(b * NC + c) * OS + yy];
  }
  for (int off = 32; off > 0; off >>= 1) acc += __shfl_down(acc, off, 64);
  __shared__ float wsum[4];
  int wid = t >> 6, lane = t & 63;
  if (lane == 0) wsum[wid] = acc;
  __syncthreads();
  if (t == 0) means[b] = (wsum[0] + wsum[1] + wsum[2] + wsum[3]) / (float)PIX;
}

// ---------------- color jitter (brightness/contrast/saturation/hue) --------
__device__ __forceinline__ float clip01(float x) { return fminf(fmaxf(x, 0.0f), 1.0f); }
__device__ __forceinline__ float fmod1(float x)  { return x - floorf(x); }  // pythonic % 1

__global__ __launch_bounds__(256) void k_jitter(const float* __restrict__ xc,
                                                const float* __restrict__ means,
                                                const float* __restrict__ prm,
                                                float* __restrict__ xj) {
  int idx = blockIdx.x * 256 + threadIdx.x;
  if (idx >= NB * PIX) return;
  int b = idx / PIX, p = idx - b * PIX;
  const float* P = prm + b * PSTRIDE;
  float bfac = P[6], cfac = P[7], sfac = P[8], hfac = P[9];
  bool cj = P[10] != 0.0f;
  size_t base = (size_t)b * NC * PIX + p;
  float r = xc[base], g = xc[base + PIX], bb = xc[base + 2 * PIX];
  if (cj) {
    float mg = means[b];
    r = clip01(r * bfac); g = clip01(g * bfac); bb = clip01(bb * bfac);
    r  = clip01(cfac * r  + (1.0f - cfac) * mg);
    g  = clip01(cfac * g  + (1.0f - cfac) * mg);
    bb = clip01(cfac * bb + (1.0f - cfac) * mg);
    float gray = 0.2989f * r + 0.587f * g + 0.114f * bb;
    r  = clip01(sfac * r  + (1.0f - sfac) * gray);
    g  = clip01(sfac * g  + (1.0f - sfac) * gray);
    bb = clip01(sfac * bb + (1.0f - sfac) * gray);
    // rgb -> hsv (reference's formulation)
    float maxc = fmaxf(r, fmaxf(g, bb));
    float minc = fminf(r, fminf(g, bb));
    float v = maxc, d = maxc - minc;
    float s = (maxc > 0.0f) ? (d / maxc) : 0.0f;
    float dn = (d > 0.0f) ? d : 1.0f;
    float rc = (maxc - r) / dn, gc = (maxc - g) / dn, bc2 = (maxc - bb) / dn;
    float h = (maxc == r) ? (bc2 - gc)
            : ((maxc == g) ? (2.0f + rc - bc2) : (4.0f + gc - rc));
    h = (d > 0.0f) ? fmod1(h / 6.0f) : 0.0f;
    h = fmod1(h + hfac);
    // hsv -> rgb
    float fi = floorf(h * 6.0f);
    float f = h * 6.0f - fi;
    int i = ((int)fi) % 6;
    float pp = v * (1.0f - s);
    float q  = v * (1.0f - s * f);
    float tt = v * (1.0f - s * (1.0f - f));
    switch (i) {
      case 0: r = v;  g = tt; bb = pp; break;
      case 1: r = q;  g = v;  bb = pp; break;
      case 2: r = pp; g = v;  bb = tt; break;
      case 3: r = pp; g = q;  bb = v;  break;
      case 4: r = tt; g = pp; bb = v;  break;
      default: r = v; g = pp; bb = q;  break;
    }
  }
  xj[base] = r; xj[base + PIX] = g; xj[base + 2 * PIX] = bb;
}

// ---------------- separable gaussian blur (reflect pad), per-b gated -------
__global__ __launch_bounds__(256) void k_blury(const float* __restrict__ xj,
                                               float* __restrict__ tmp,
                                               const float* __restrict__ prm) {
  int idx = blockIdx.x * 256 + threadIdx.x;
  if (idx >= NB * NC * PIX) return;
  int b = idx / (NC * PIX);
  const float* P = prm + b * PSTRIDE;
  if (P[11] == 0.0f) return;                 // blur not applied to this sample
  int rem = idx - b * NC * PIX;
  int p = rem % PIX;
  int y = p / OS, xq = p - y * OS;
  const float* plane = xj + (size_t)(idx - p);
  float acc = 0.0f;
  #pragma unroll
  for (int k = 0; k < 15; ++k) {
    int yy = y + k - 7;
    yy = (yy < 0) ? -yy : ((yy > OS - 1) ? (2 * (OS - 1) - yy) : yy);
    acc += P[12 + k] * plane[yy * OS + xq];
  }
  tmp[idx] = acc;
}

__global__ __launch_bounds__(256) void k_blurx(const float* __restrict__ tmp,
                                               float* __restrict__ out,
                                               const float* __restrict__ prm) {
  int idx = blockIdx.x * 256 + threadIdx.x;
  if (idx >= NB * NC * PIX) return;
  int b = idx / (NC * PIX);
  const float* P = prm + b * PSTRIDE;
  if (P[11] == 0.0f) return;                 // keep xj already in out
  int p = idx % PIX;
  int xq = p % OS;
  const float* row = tmp + (size_t)(idx - xq);
  float acc = 0.0f;
  #pragma unroll
  for (int k = 0; k < 15; ++k) {
    int xx = xq + k - 7;
    xx = (xx < 0) ? -xx : ((xx > OS - 1) ? (2 * (OS - 1) - xx) : xx);
    acc += P[12 + k] * row[xx];
  }
  out[idx] = acc;
}

// ---------------- launch ----------------
extern "C" void kernel_launch(void* const* d_in, const int* in_sizes, int n_in,
                              void* d_out, int out_size, void* d_ws, size_t ws_size,
                              hipStream_t stream) {
  const float* x = (const float*)d_in[0];
  float* out = (float*)d_out;
  char* ws = (char*)d_ws;

  float* prm    = (float*)ws;                                  // 32768 B
  float* rowsum = (float*)(ws + 32768);                        // 688128 B
  float* means  = (float*)(ws + 32768 + 688128);               // 1024 B
  float* bufA   = (float*)(ws + 32768 + 688128 + 1024);        // 154140672 B (xc, then blur tmp)

  k_params<<<1, 256, 0, stream>>>(prm);
  k_resize<<<NB * NC * OS, 256, 0, stream>>>(x, bufA, rowsum, prm);
  k_means<<<NB, 256, 0, stream>>>(rowsum, means);

  int npix = NB * PIX;
  k_jitter<<<(npix + 255) / 256, 256, 0, stream>>>(bufA, means, prm, out);   // xj -> d_out

  int nall = NB * NC * PIX;
  k_blury<<<(nall + 255) / 256, 256, 0, stream>>>(out, bufA, prm);           // xj -> tmp (blur b only)
  k_blurx<<<(nall + 255) / 256, 256, 0, stream>>>(bufA, out, prm);           // tmp -> out (blur b only)
}

// Round 2
// 264.377 us; speedup vs baseline: 4.7060x; 4.7060x over previous
//
#include <hip/hip_runtime.h>
#include <cstdint>
#include <cstddef>

// ============================================================================
// MildAugmentStage: random-resized-crop (cubic, antialias) + color jitter +
// separable gaussian blur, reproducing jax.random (threefry2x32) exactly.
// Round 1: tiled separable resize (weights amortized per block), fused blur.
// ============================================================================

#define JAX_PARTITIONABLE 1

#define NB 256
#define NC 3
#define IH 256
#define IW 256
#define OS 224
#define PIX (OS * OS)         // 50176
#define PSTRIDE 32            // floats per batch param slot
#define TROWS 16              // output rows per resize/blur tile
#define LROWS 24              // max staged input rows (bound: 15*1.143+4*1.143+1 < 23)
#define NTILE 14              // 224/16

// param slot layout (floats):
// 0 inv_sy, 1 tiy, 2 ksy, 3 inv_sx, 4 tix, 5 ksx,
// 6 bf, 7 cf, 8 sf, 9 hf, 10 cj, 11 bl, 12..26 kern[15]

// ---------------- threefry-2x32 (JAX rotation/key schedule) ----------------
__device__ __forceinline__ void tf2x32(uint32_t k0, uint32_t k1,
                                       uint32_t x0, uint32_t x1,
                                       uint32_t& o0, uint32_t& o1) {
  uint32_t ks[3] = {k0, k1, k0 ^ k1 ^ 0x1BD11BDAu};
  uint32_t a = x0 + ks[0], b = x1 + ks[1];
  const int R[2][4] = {{13, 15, 26, 6}, {17, 29, 16, 24}};
  #pragma unroll
  for (int i = 0; i < 5; ++i) {
    #pragma unroll
    for (int j = 0; j < 4; ++j) {
      int r = R[i & 1][j];
      a += b;
      b = (b << r) | (b >> (32 - r));
      b ^= a;
    }
    a += ks[(i + 1) % 3];
    b += ks[(i + 2) % 3] + (uint32_t)(i + 1);
  }
  o0 = a; o1 = b;
}

__device__ __forceinline__ float bits_to_u01(uint32_t bits) {
  uint32_t fb = (bits >> 9) | 0x3f800000u;
  return __uint_as_float(fb) - 1.0f;
}

__device__ __forceinline__ float u01_n(uint32_t k0, uint32_t k1, uint32_t i, uint32_t N) {
#if JAX_PARTITIONABLE
  uint32_t a, b; tf2x32(k0, k1, 0u, i, a, b);
  return bits_to_u01(a ^ b);
#else
  uint32_t half = N >> 1;
  uint32_t a, b;
  if (i < half) { tf2x32(k0, k1, i, half + i, a, b); return bits_to_u01(a); }
  tf2x32(k0, k1, i - half, i, a, b); return bits_to_u01(b);
#endif
}

__device__ __forceinline__ float junif(uint32_t k0, uint32_t k1, uint32_t i, uint32_t N,
                                       float mn, float mx) {
  float u = u01_n(k0, k1, i, N);
  float d = __fsub_rn(mx, mn);
  float r = __fadd_rn(__fmul_rn(u, d), mn);
  return fmaxf(mn, r);
}

// ---------------- per-batch augmentation parameters ----------------
__global__ __launch_bounds__(256) void k_params(float* __restrict__ prm) {
  int b = threadIdx.x;
  if (b >= NB) return;
  uint32_t ks[10][2];
#if JAX_PARTITIONABLE
  for (int j = 0; j < 10; ++j) tf2x32(0u, 42u, 0u, (uint32_t)j, ks[j][0], ks[j][1]);
#else
  {
    uint32_t flat[20];
    for (int j = 0; j < 10; ++j) {
      uint32_t a, bb; tf2x32(0u, 42u, (uint32_t)j, (uint32_t)(10 + j), a, bb);
      flat[j] = a; flat[10 + j] = bb;
    }
    for (int j = 0; j < 10; ++j) { ks[j][0] = flat[2 * j]; ks[j][1] = flat[2 * j + 1]; }
  }
#endif
  float* P = prm + b * PSTRIDE;

  float uarea = junif(ks[0][0], ks[0][1], b, NB, 0.8f, 1.0f);
  float area  = __fmul_rn(65536.0f, uarea);
  float lmn = (float)(-0.28768207245178085);
  float lmx = (float)( 0.28768207245178085);
  float ur  = junif(ks[1][0], ks[1][1], b, NB, lmn, lmx);
  float ratio = (float)exp((double)ur);

  float cw = rintf(__fsqrt_rn(__fmul_rn(area, ratio)));
  cw = fminf(fmaxf(cw, 1.0f), 256.0f);
  float ch = rintf(__fsqrt_rn(__fdiv_rn(area, ratio)));
  ch = fminf(fmaxf(ch, 1.0f), 256.0f);

  float ui = u01_n(ks[2][0], ks[2][1], b, NB);
  float uj = u01_n(ks[3][0], ks[3][1], b, NB);
  float i0 = floorf(__fmul_rn(ui, __fadd_rn(__fsub_rn(256.0f, ch), 1.0f)));
  float j0 = floorf(__fmul_rn(uj, __fadd_rn(__fsub_rn(256.0f, cw), 1.0f)));

  float sy = __fdiv_rn(224.0f, ch), sx = __fdiv_rn(224.0f, cw);
  float ty = -__fmul_rn(i0, sy),   tx = -__fmul_rn(j0, sx);
  float inv_sy = __fdiv_rn(1.0f, sy), inv_sx = __fdiv_rn(1.0f, sx);
  P[0] = inv_sy;
  P[1] = __fmul_rn(ty, inv_sy);
  P[2] = fmaxf(inv_sy, 1.0f);
  P[3] = inv_sx;
  P[4] = __fmul_rn(tx, inv_sx);
  P[5] = fmaxf(inv_sx, 1.0f);

  P[6] = junif(ks[4][0], ks[4][1], b, NB, 0.9f, 1.1f);
  P[7] = junif(ks[5][0], ks[5][1], b, NB, 0.9f, 1.1f);
  P[8] = junif(ks[6][0], ks[6][1], b, NB, 0.9f, 1.1f);
  P[9] = junif(ks[7][0], ks[7][1], b, NB, -0.01f, 0.01f);
  P[10] = (u01_n(ks[8][0], ks[8][1], b, NB) < 0.8f) ? 1.0f : 0.0f;

  uint32_t kb0[2], kb1[2];
#if JAX_PARTITIONABLE
  tf2x32(ks[9][0], ks[9][1], 0u, 0u, kb0[0], kb0[1]);
  tf2x32(ks[9][0], ks[9][1], 0u, 1u, kb1[0], kb1[1]);
#else
  {
    uint32_t f0, s0, f1, s1;
    tf2x32(ks[9][0], ks[9][1], 0u, 2u, f0, s0);
    tf2x32(ks[9][0], ks[9][1], 1u, 3u, f1, s1);
    kb0[0] = f0; kb0[1] = f1; kb1[0] = s0; kb1[1] = s1;
  }
#endif
  float sg = junif(kb0[0], kb0[1], b, NB, 0.1f, 2.0f);
  P[11] = (u01_n(kb1[0], kb1[1], b, NB) < 0.5f) ? 1.0f : 0.0f;

  float e[15]; float ssum = 0.0f;
  for (int k = 0; k < 15; ++k) {
    float t = (float)k - 7.0f;
    float z = t / sg;
    e[k] = expf(-0.5f * (z * z));
    ssum += e[k];
  }
  for (int k = 0; k < 15; ++k) P[12 + k] = e[k] / ssum;
}

// ---------------- cubic (Keys, a=-0.5) ----------------
__device__ __forceinline__ float keys_cubic(float x) {
  float o = ((1.5f * x - 2.5f) * x) * x + 1.0f;
  if (x >= 1.0f) o = ((-0.5f * x + 2.5f) * x - 4.0f) * x + 2.0f;
  if (x >= 2.0f) o = 0.0f;
  return o;
}

// ---------------- tiled separable resize: block = (b,c,16-row tile) --------
__global__ __launch_bounds__(256) void k_resize(const float* __restrict__ x,
                                                float* __restrict__ xc,
                                                float* __restrict__ rowsum,
                                                const float* __restrict__ prm) {
  int blk = blockIdx.x;
  int tile = blk % NTILE;
  int c = (blk / NTILE) % NC;
  int b = blk / (NTILE * NC);
  const float* P = prm + b * PSTRIDE;
  int t = threadIdx.x;
  int oyb = tile * TROWS;

  __shared__ float s_wy[TROWS][8];       // idx, w0..w5, pad
  __shared__ float s_in[LROWS][256];
  __shared__ float s_ty[TROWS][256];

  // per-lane x weights (computed once, reused for 16 rows)
  float wx[6]; int ix0 = 0;
  if (t < OS) {
    float inv_sx = P[3], tix = P[4], ksx = P[5];
    float sfx = ((float)t + 0.5f) * inv_sx - tix - 0.5f;
    float rx = 2.0f * ksx;
    ix0 = max(0, (int)ceilf(sfx - rx));
    int ix1 = min(IW - 1, (int)floorf(sfx + rx));
    int nx = ix1 - ix0 + 1; if (nx > 6) nx = 6;
    float tot = 0.0f;
    #pragma unroll
    for (int j = 0; j < 6; ++j) {
      float w = 0.0f;
      if (j < nx) { float d = fabsf(sfx - (float)(ix0 + j)) / ksx; w = keys_cubic(d); }
      wx[j] = w; tot += w;
    }
    if (fabsf(tot) > 1.1920929e-4f) { float ri = 1.0f / tot; for (int j = 0; j < 6; ++j) wx[j] *= ri; }
    else                            { for (int j = 0; j < 6; ++j) wx[j] = 0.0f; }
  }

  // y weights: 16 threads, one per output row of the tile
  if (t < TROWS) {
    float inv_sy = P[0], tiy = P[1], ksy = P[2];
    int oy = oyb + t;
    float sfy = ((float)oy + 0.5f) * inv_sy - tiy - 0.5f;
    float ry = 2.0f * ksy;
    int iy0 = max(0, (int)ceilf(sfy - ry));
    int iy1 = min(IH - 1, (int)floorf(sfy + ry));
    int nyy = iy1 - iy0 + 1; if (nyy > 6) nyy = 6;
    float w6[6]; float tot = 0.0f;
    #pragma unroll
    for (int j = 0; j < 6; ++j) {
      float w = 0.0f;
      if (j < nyy) { float d = fabsf(sfy - (float)(iy0 + j)) / ksy; w = keys_cubic(d); }
      w6[j] = w; tot += w;
    }
    float ri = (fabsf(tot) > 1.1920929e-4f) ? (1.0f / tot) : 0.0f;
    s_wy[t][0] = (float)iy0;
    #pragma unroll
    for (int j = 0; j < 6; ++j) s_wy[t][1 + j] = w6[j] * ri;
  }
  __syncthreads();

  int base = (int)s_wy[0][0];
  int rows = min(IH, (int)s_wy[TROWS - 1][0] + 6) - base;
  if (rows > LROWS) rows = LROWS;

  const float* src = x + ((size_t)(b * NC + c) * IH + base) * IW;
  for (int r = 0; r < rows; ++r) s_in[r][t] = src[(size_t)r * IW + t];
  __syncthreads();

  // y-pass: thread t = input column (all 256)
  for (int i = 0; i < TROWS; ++i) {
    int ry0 = (int)s_wy[i][0] - base;
    float acc = 0.0f;
    #pragma unroll
    for (int j = 0; j < 6; ++j) {
      int rr = ry0 + j; if (rr > rows - 1) rr = rows - 1;
      acc += s_wy[i][1 + j] * s_in[rr][t];
    }
    s_ty[i][t] = acc;
  }
  __syncthreads();

  // x-pass + partial sum of clip(xc*bf) for mean_gray
  float bfac = P[6];
  float psum = 0.0f;
  if (t < OS) {
    float* dst = xc + ((size_t)(b * NC + c) * OS + oyb) * OS + t;
    for (int i = 0; i < TROWS; ++i) {
      float acc = 0.0f;
      #pragma unroll
      for (int j = 0; j < 6; ++j) {
        int xx = ix0 + j; if (xx > IW - 1) xx = IW - 1;
        acc += wx[j] * s_ty[i][xx];
      }
      dst[(size_t)i * OS] = acc;
      psum += fminf(fmaxf(acc * bfac, 0.0f), 1.0f);
    }
  }
  for (int off = 32; off > 0; off >>= 1) psum += __shfl_down(psum, off, 64);
  __shared__ float wsum[4];
  int wid = t >> 6, lane = t & 63;
  if (lane == 0) wsum[wid] = psum;
  __syncthreads();
  if (t == 0) rowsum[blk] = wsum[0] + wsum[1] + wsum[2] + wsum[3];
}

__global__ __launch_bounds__(64) void k_means(const float* __restrict__ rowsum,
                                              float* __restrict__ means) {
  int b = blockIdx.x, t = threadIdx.x;
  float acc = 0.0f;
  if (t < NC * NTILE) {
    int c = t / NTILE;
    float w = (c == 0) ? 0.2989f : ((c == 1) ? 0.587f : 0.114f);
    acc = w * rowsum[b * NC * NTILE + t];
  }
  for (int off = 32; off > 0; off >>= 1) acc += __shfl_down(acc, off, 64);
  if (t == 0) means[b] = acc / (float)PIX;
}

// ---------------- color jitter ----------------
__device__ __forceinline__ float clip01(float x) { return fminf(fmaxf(x, 0.0f), 1.0f); }
__device__ __forceinline__ float fmod1(float x)  { return x - floorf(x); }

// reads xc from `xc` (=d_out), writes xj to bufA always + to out for non-blur b
__global__ __launch_bounds__(256) void k_jitter(const float* __restrict__ xc,
                                                const float* __restrict__ means,
                                                const float* __restrict__ prm,
                                                float* __restrict__ xj,
                                                float* __restrict__ out) {
  int idx = blockIdx.x * 256 + threadIdx.x;
  if (idx >= NB * PIX) return;
  int b = idx / PIX, p = idx - b * PIX;
  const float* P = prm + b * PSTRIDE;
  float bfac = P[6], cfac = P[7], sfac = P[8], hfac = P[9];
  bool cj = P[10] != 0.0f;
  bool bl = P[11] != 0.0f;
  size_t base = (size_t)b * NC * PIX + p;
  float r = xc[base], g = xc[base + PIX], bb = xc[base + 2 * PIX];
  if (cj) {
    float mg = means[b];
    r = clip01(r * bfac); g = clip01(g * bfac); bb = clip01(bb * bfac);
    r  = clip01(cfac * r  + (1.0f - cfac) * mg);
    g  = clip01(cfac * g  + (1.0f - cfac) * mg);
    bb = clip01(cfac * bb + (1.0f - cfac) * mg);
    float gray = 0.2989f * r + 0.587f * g + 0.114f * bb;
    r  = clip01(sfac * r  + (1.0f - sfac) * gray);
    g  = clip01(sfac * g  + (1.0f - sfac) * gray);
    bb = clip01(sfac * bb + (1.0f - sfac) * gray);
    float maxc = fmaxf(r, fmaxf(g, bb));
    float minc = fminf(r, fminf(g, bb));
    float v = maxc, d = maxc - minc;
    float s = (maxc > 0.0f) ? (d / maxc) : 0.0f;
    float dn = (d > 0.0f) ? d : 1.0f;
    float rc = (maxc - r) / dn, gc = (maxc - g) / dn, bc2 = (maxc - bb) / dn;
    float h = (maxc == r) ? (bc2 - gc)
            : ((maxc == g) ? (2.0f + rc - bc2) : (4.0f + gc - rc));
    h = (d > 0.0f) ? fmod1(h / 6.0f) : 0.0f;
    h = fmod1(h + hfac);
    float fi = floorf(h * 6.0f);
    float f = h * 6.0f - fi;
    int i = ((int)fi) % 6;
    float pp = v * (1.0f - s);
    float q  = v * (1.0f - s * f);
    float tt = v * (1.0f - s * (1.0f - f));
    switch (i) {
      case 0: r = v;  g = tt; bb = pp; break;
      case 1: r = q;  g = v;  bb = pp; break;
      case 2: r = pp; g = v;  bb = tt; break;
      case 3: r = pp; g = q;  bb = v;  break;
      case 4: r = tt; g = pp; bb = v;  break;
      default: r = v; g = pp; bb = q;  break;
    }
  }
  xj[base] = r; xj[base + PIX] = g; xj[base + 2 * PIX] = bb;
  if (!bl) { out[base] = r; out[base + PIX] = g; out[base + 2 * PIX] = bb; }
}

// ---------------- fused separable gaussian blur (reflect), gated per b -----
__global__ __launch_bounds__(256) void k_blur(const float* __restrict__ xj,
                                              float* __restrict__ out,
                                              const float* __restrict__ prm) {
  int blk = blockIdx.x;
  int tile = blk % NTILE;
  int c = (blk / NTILE) % NC;
  int b = blk / (NTILE * NC);
  const float* P = prm + b * PSTRIDE;
  if (P[11] == 0.0f) return;           // jitter already wrote out for non-blur b
  int t = threadIdx.x;
  int oyb = tile * TROWS;

  __shared__ float s_in[TROWS + 14][OS];
  __shared__ float s_mid[TROWS][OS];
  __shared__ float s_k[15];
  if (t < 15) s_k[t] = P[12 + t];
  const float* plane = xj + (size_t)(b * NC + c) * PIX;
  float* oplane = out + (size_t)(b * NC + c) * PIX;
  if (t < OS) {
    for (int r = 0; r < TROWS + 14; ++r) {
      int yy = oyb - 7 + r;
      yy = (yy < 0) ? -yy : ((yy > OS - 1) ? (2 * (OS - 1) - yy) : yy);
      s_in[r][t] = plane[(size_t)yy * OS + t];
    }
  }
  __syncthreads();
  if (t < OS) {
    for (int i = 0; i < TROWS; ++i) {
      float acc = 0.0f;
      #pragma unroll
      for (int k = 0; k < 15; ++k) acc += s_k[k] * s_in[i + k][t];
      s_mid[i][t] = acc;
    }
  }
  __syncthreads();
  if (t < OS) {
    for (int i = 0; i < TROWS; ++i) {
      float acc = 0.0f;
      #pragma unroll
      for (int k = 0; k < 15; ++k) {
        int xx = t - 7 + k;
        xx = (xx < 0) ? -xx : ((xx > OS - 1) ? (2 * (OS - 1) - xx) : xx);
        acc += s_k[k] * s_mid[i][xx];
      }
      oplane[(size_t)(oyb + i) * OS + t] = acc;
    }
  }
}

// ---------------- launch ----------------
extern "C" void kernel_launch(void* const* d_in, const int* in_sizes, int n_in,
                              void* d_out, int out_size, void* d_ws, size_t ws_size,
                              hipStream_t stream) {
  const float* x = (const float*)d_in[0];
  float* out = (float*)d_out;
  char* ws = (char*)d_ws;

  float* prm    = (float*)ws;                          // 32768 B
  float* rowsum = (float*)(ws + 32768);                // 10752*4 = 43008 B
  float* means  = (float*)(ws + 32768 + 43008);        // 1024 B
  float* bufA   = (float*)(ws + 76800);                // 154140672 B (xj)

  k_params<<<1, 256, 0, stream>>>(prm);

  int nblk = NB * NC * NTILE;                          // 10752
  k_resize<<<nblk, 256, 0, stream>>>(x, out, rowsum, prm);   // xc -> d_out
  k_means<<<NB, 64, 0, stream>>>(rowsum, means);

  int npix = NB * PIX;
  k_jitter<<<(npix + 255) / 256, 256, 0, stream>>>(out, means, prm, bufA, out);

  k_blur<<<nblk, 256, 0, stream>>>(bufA, out, prm);    // blurred b: bufA -> out
}

// Round 3
// 218.278 us; speedup vs baseline: 5.6999x; 1.2112x over previous
//
#include <hip/hip_runtime.h>
#include <cstdint>
#include <cstddef>

// ============================================================================
// MildAugmentStage: random-resized-crop (cubic, antialias) + color jitter +
// separable gaussian blur, reproducing jax.random (threefry2x32) exactly.
// Round 2: x-first resize with in-place LDS (25KB -> 6 blocks/CU), float4
// staging, single-destination jitter writes, float4 jitter/blur.
// ============================================================================

#define JAX_PARTITIONABLE 1

#define NB 256
#define NC 3
#define IH 256
#define IW 256
#define OS 224
#define PIX (OS * OS)         // 50176
#define PSTRIDE 32
#define TROWS 16              // output rows per resize/blur tile
#define LROWS 24              // max staged input rows
#define NTILE 14              // 224/16

// ---------------- threefry-2x32 ----------------
__device__ __forceinline__ void tf2x32(uint32_t k0, uint32_t k1,
                                       uint32_t x0, uint32_t x1,
                                       uint32_t& o0, uint32_t& o1) {
  uint32_t ks[3] = {k0, k1, k0 ^ k1 ^ 0x1BD11BDAu};
  uint32_t a = x0 + ks[0], b = x1 + ks[1];
  const int R[2][4] = {{13, 15, 26, 6}, {17, 29, 16, 24}};
  #pragma unroll
  for (int i = 0; i < 5; ++i) {
    #pragma unroll
    for (int j = 0; j < 4; ++j) {
      int r = R[i & 1][j];
      a += b;
      b = (b << r) | (b >> (32 - r));
      b ^= a;
    }
    a += ks[(i + 1) % 3];
    b += ks[(i + 2) % 3] + (uint32_t)(i + 1);
  }
  o0 = a; o1 = b;
}

__device__ __forceinline__ float bits_to_u01(uint32_t bits) {
  uint32_t fb = (bits >> 9) | 0x3f800000u;
  return __uint_as_float(fb) - 1.0f;
}

__device__ __forceinline__ float u01_n(uint32_t k0, uint32_t k1, uint32_t i, uint32_t N) {
#if JAX_PARTITIONABLE
  uint32_t a, b; tf2x32(k0, k1, 0u, i, a, b);
  return bits_to_u01(a ^ b);
#else
  uint32_t half = N >> 1;
  uint32_t a, b;
  if (i < half) { tf2x32(k0, k1, i, half + i, a, b); return bits_to_u01(a); }
  tf2x32(k0, k1, i - half, i, a, b); return bits_to_u01(b);
#endif
}

__device__ __forceinline__ float junif(uint32_t k0, uint32_t k1, uint32_t i, uint32_t N,
                                       float mn, float mx) {
  float u = u01_n(k0, k1, i, N);
  float d = __fsub_rn(mx, mn);
  float r = __fadd_rn(__fmul_rn(u, d), mn);
  return fmaxf(mn, r);
}

// ---------------- per-batch augmentation parameters ----------------
__global__ __launch_bounds__(256) void k_params(float* __restrict__ prm) {
  int b = threadIdx.x;
  if (b >= NB) return;
  uint32_t ks[10][2];
#if JAX_PARTITIONABLE
  for (int j = 0; j < 10; ++j) tf2x32(0u, 42u, 0u, (uint32_t)j, ks[j][0], ks[j][1]);
#else
  {
    uint32_t flat[20];
    for (int j = 0; j < 10; ++j) {
      uint32_t a, bb; tf2x32(0u, 42u, (uint32_t)j, (uint32_t)(10 + j), a, bb);
      flat[j] = a; flat[10 + j] = bb;
    }
    for (int j = 0; j < 10; ++j) { ks[j][0] = flat[2 * j]; ks[j][1] = flat[2 * j + 1]; }
  }
#endif
  float* P = prm + b * PSTRIDE;

  float uarea = junif(ks[0][0], ks[0][1], b, NB, 0.8f, 1.0f);
  float area  = __fmul_rn(65536.0f, uarea);
  float lmn = (float)(-0.28768207245178085);
  float lmx = (float)( 0.28768207245178085);
  float ur  = junif(ks[1][0], ks[1][1], b, NB, lmn, lmx);
  float ratio = (float)exp((double)ur);

  float cw = rintf(__fsqrt_rn(__fmul_rn(area, ratio)));
  cw = fminf(fmaxf(cw, 1.0f), 256.0f);
  float ch = rintf(__fsqrt_rn(__fdiv_rn(area, ratio)));
  ch = fminf(fmaxf(ch, 1.0f), 256.0f);

  float ui = u01_n(ks[2][0], ks[2][1], b, NB);
  float uj = u01_n(ks[3][0], ks[3][1], b, NB);
  float i0 = floorf(__fmul_rn(ui, __fadd_rn(__fsub_rn(256.0f, ch), 1.0f)));
  float j0 = floorf(__fmul_rn(uj, __fadd_rn(__fsub_rn(256.0f, cw), 1.0f)));

  float sy = __fdiv_rn(224.0f, ch), sx = __fdiv_rn(224.0f, cw);
  float ty = -__fmul_rn(i0, sy),   tx = -__fmul_rn(j0, sx);
  float inv_sy = __fdiv_rn(1.0f, sy), inv_sx = __fdiv_rn(1.0f, sx);
  P[0] = inv_sy;
  P[1] = __fmul_rn(ty, inv_sy);
  P[2] = fmaxf(inv_sy, 1.0f);
  P[3] = inv_sx;
  P[4] = __fmul_rn(tx, inv_sx);
  P[5] = fmaxf(inv_sx, 1.0f);

  P[6] = junif(ks[4][0], ks[4][1], b, NB, 0.9f, 1.1f);
  P[7] = junif(ks[5][0], ks[5][1], b, NB, 0.9f, 1.1f);
  P[8] = junif(ks[6][0], ks[6][1], b, NB, 0.9f, 1.1f);
  P[9] = junif(ks[7][0], ks[7][1], b, NB, -0.01f, 0.01f);
  P[10] = (u01_n(ks[8][0], ks[8][1], b, NB) < 0.8f) ? 1.0f : 0.0f;

  uint32_t kb0[2], kb1[2];
#if JAX_PARTITIONABLE
  tf2x32(ks[9][0], ks[9][1], 0u, 0u, kb0[0], kb0[1]);
  tf2x32(ks[9][0], ks[9][1], 0u, 1u, kb1[0], kb1[1]);
#else
  {
    uint32_t f0, s0, f1, s1;
    tf2x32(ks[9][0], ks[9][1], 0u, 2u, f0, s0);
    tf2x32(ks[9][0], ks[9][1], 1u, 3u, f1, s1);
    kb0[0] = f0; kb0[1] = f1; kb1[0] = s0; kb1[1] = s1;
  }
#endif
  float sg = junif(kb0[0], kb0[1], b, NB, 0.1f, 2.0f);
  P[11] = (u01_n(kb1[0], kb1[1], b, NB) < 0.5f) ? 1.0f : 0.0f;

  float e[15]; float ssum = 0.0f;
  for (int k = 0; k < 15; ++k) {
    float t = (float)k - 7.0f;
    float z = t / sg;
    e[k] = expf(-0.5f * (z * z));
    ssum += e[k];
  }
  for (int k = 0; k < 15; ++k) P[12 + k] = e[k] / ssum;
}

// ---------------- cubic (Keys, a=-0.5) ----------------
__device__ __forceinline__ float keys_cubic(float x) {
  float o = ((1.5f * x - 2.5f) * x) * x + 1.0f;
  if (x >= 1.0f) o = ((-0.5f * x + 2.5f) * x - 4.0f) * x + 2.0f;
  if (x >= 2.0f) o = 0.0f;
  return o;
}

// ---------------- tiled separable resize, x-pass first, in-place LDS ------
__global__ __launch_bounds__(256) void k_resize(const float* __restrict__ x,
                                                float* __restrict__ xc,
                                                float* __restrict__ rowsum,
                                                const float* __restrict__ prm) {
  int blk = blockIdx.x;
  int tile = blk % NTILE;
  int c = (blk / NTILE) % NC;
  int b = blk / (NTILE * NC);
  const float* P = prm + b * PSTRIDE;
  int t = threadIdx.x;
  int oyb = tile * TROWS;

  __shared__ float s_wy[TROWS][8];       // iy0, w0..w5, pad
  __shared__ float s_in[LROWS][256];     // 24.5 KB — raw rows, then x-resized in place

  // per-lane x weights
  float wx[6]; int ix0 = 0;
  if (t < OS) {
    float inv_sx = P[3], tix = P[4], ksx = P[5];
    float sfx = ((float)t + 0.5f) * inv_sx - tix - 0.5f;
    float rx = 2.0f * ksx;
    ix0 = max(0, (int)ceilf(sfx - rx));
    int ix1 = min(IW - 1, (int)floorf(sfx + rx));
    int nx = ix1 - ix0 + 1; if (nx > 6) nx = 6;
    float tot = 0.0f;
    #pragma unroll
    for (int j = 0; j < 6; ++j) {
      float w = 0.0f;
      if (j < nx) { float d = fabsf(sfx - (float)(ix0 + j)) / ksx; w = keys_cubic(d); }
      wx[j] = w; tot += w;
    }
    if (fabsf(tot) > 1.1920929e-4f) { float ri = 1.0f / tot; for (int j = 0; j < 6; ++j) wx[j] *= ri; }
    else                            { for (int j = 0; j < 6; ++j) wx[j] = 0.0f; }
  }

  // y weights: 16 threads
  if (t < TROWS) {
    float inv_sy = P[0], tiy = P[1], ksy = P[2];
    int oy = oyb + t;
    float sfy = ((float)oy + 0.5f) * inv_sy - tiy - 0.5f;
    float ry = 2.0f * ksy;
    int iy0 = max(0, (int)ceilf(sfy - ry));
    int iy1 = min(IH - 1, (int)floorf(sfy + ry));
    int nyy = iy1 - iy0 + 1; if (nyy > 6) nyy = 6;
    float w6[6]; float tot = 0.0f;
    #pragma unroll
    for (int j = 0; j < 6; ++j) {
      float w = 0.0f;
      if (j < nyy) { float d = fabsf(sfy - (float)(iy0 + j)) / ksy; w = keys_cubic(d); }
      w6[j] = w; tot += w;
    }
    float ri = (fabsf(tot) > 1.1920929e-4f) ? (1.0f / tot) : 0.0f;
    s_wy[t][0] = (float)iy0;
    #pragma unroll
    for (int j = 0; j < 6; ++j) s_wy[t][1 + j] = w6[j] * ri;
  }
  __syncthreads();

  int base = (int)s_wy[0][0];
  int rows = min(IH, (int)s_wy[TROWS - 1][0] + 6) - base;
  if (rows > LROWS) rows = LROWS;

  // contiguous float4 staging of `rows` full-width input rows
  {
    const float4* src4 = (const float4*)(x + ((size_t)(b * NC + c) * IH + base) * IW);
    float4* s4 = (float4*)&s_in[0][0];
    int nvec = rows * (IW / 4);
    for (int i = t; i < nvec; i += 256) s4[i] = src4[i];
  }
  __syncthreads();

  // x-pass into registers (static-indexed, unrolled)
  float xr[LROWS];
  if (t < OS) {
    #pragma unroll
    for (int r = 0; r < LROWS; ++r) {
      float acc = 0.0f;
      #pragma unroll
      for (int j = 0; j < 6; ++j) {
        int xx = ix0 + j; if (xx > IW - 1) xx = IW - 1;
        acc += wx[j] * s_in[r][xx];
      }
      xr[r] = acc;
    }
  }
  __syncthreads();
  // write back in place: s_in[r][0..223] now holds x-resized rows
  if (t < OS) {
    #pragma unroll
    for (int r = 0; r < LROWS; ++r) s_in[r][t] = xr[r];
  }
  __syncthreads();

  // y-pass + partial sum of clip(xc*bf) for mean_gray
  float bfac = P[6];
  float psum = 0.0f;
  if (t < OS) {
    float* dst = xc + ((size_t)(b * NC + c) * OS + oyb) * OS + t;
    for (int i = 0; i < TROWS; ++i) {
      int ry0 = (int)s_wy[i][0] - base;
      float acc = 0.0f;
      #pragma unroll
      for (int j = 0; j < 6; ++j) {
        int rr = ry0 + j; if (rr > rows - 1) rr = rows - 1;
        acc += s_wy[i][1 + j] * s_in[rr][t];
      }
      dst[(size_t)i * OS] = acc;
      psum += fminf(fmaxf(acc * bfac, 0.0f), 1.0f);
    }
  }
  for (int off = 32; off > 0; off >>= 1) psum += __shfl_down(psum, off, 64);
  __shared__ float wsum[4];
  int wid = t >> 6, lane = t & 63;
  if (lane == 0) wsum[wid] = psum;
  __syncthreads();
  if (t == 0) rowsum[blk] = wsum[0] + wsum[1] + wsum[2] + wsum[3];
}

__global__ __launch_bounds__(64) void k_means(const float* __restrict__ rowsum,
                                              float* __restrict__ means) {
  int b = blockIdx.x, t = threadIdx.x;
  float acc = 0.0f;
  if (t < NC * NTILE) {
    int c = t / NTILE;
    float w = (c == 0) ? 0.2989f : ((c == 1) ? 0.587f : 0.114f);
    acc = w * rowsum[b * NC * NTILE + t];
  }
  for (int off = 32; off > 0; off >>= 1) acc += __shfl_down(acc, off, 64);
  if (t == 0) means[b] = acc / (float)PIX;
}

// ---------------- color jitter ----------------
__device__ __forceinline__ float clip01(float x) { return fminf(fmaxf(x, 0.0f), 1.0f); }
__device__ __forceinline__ float fmod1(float x)  { return x - floorf(x); }

__device__ __forceinline__ void jitter_px(float& r, float& g, float& bb,
                                          float mg, float bfac, float cfac,
                                          float sfac, float hfac) {
  r = clip01(r * bfac); g = clip01(g * bfac); bb = clip01(bb * bfac);
  r  = clip01(cfac * r  + (1.0f - cfac) * mg);
  g  = clip01(cfac * g  + (1.0f - cfac) * mg);
  bb = clip01(cfac * bb + (1.0f - cfac) * mg);
  float gray = 0.2989f * r + 0.587f * g + 0.114f * bb;
  r  = clip01(sfac * r  + (1.0f - sfac) * gray);
  g  = clip01(sfac * g  + (1.0f - sfac) * gray);
  bb = clip01(sfac * bb + (1.0f - sfac) * gray);
  float maxc = fmaxf(r, fmaxf(g, bb));
  float minc = fminf(r, fminf(g, bb));
  float v = maxc, d = maxc - minc;
  float s = (maxc > 0.0f) ? (d / maxc) : 0.0f;
  float dn = (d > 0.0f) ? d : 1.0f;
  float rc = (maxc - r) / dn, gc = (maxc - g) / dn, bc2 = (maxc - bb) / dn;
  float h = (maxc == r) ? (bc2 - gc)
          : ((maxc == g) ? (2.0f + rc - bc2) : (4.0f + gc - rc));
  h = (d > 0.0f) ? fmod1(h / 6.0f) : 0.0f;
  h = fmod1(h + hfac);
  float fi = floorf(h * 6.0f);
  float f = h * 6.0f - fi;
  int i = ((int)fi) % 6;
  float pp = v * (1.0f - s);
  float q  = v * (1.0f - s * f);
  float tt = v * (1.0f - s * (1.0f - f));
  switch (i) {
    case 0: r = v;  g = tt; bb = pp; break;
    case 1: r = q;  g = v;  bb = pp; break;
    case 2: r = pp; g = v;  bb = tt; break;
    case 3: r = pp; g = q;  bb = v;  break;
    case 4: r = tt; g = pp; bb = v;  break;
    default: r = v; g = pp; bb = q;  break;
  }
}

// float4: 4 pixels/thread. Blur batches -> xj buffer; non-blur -> out directly.
__global__ __launch_bounds__(256) void k_jitter(const float* __restrict__ xc,
                                                const float* __restrict__ means,
                                                const float* __restrict__ prm,
                                                float* __restrict__ xj,
                                                float* __restrict__ out) {
  int idx = blockIdx.x * 256 + threadIdx.x;          // quad index
  const int QPB = PIX / 4;                           // 12544 quads per batch
  if (idx >= NB * QPB) return;
  int b = idx / QPB, p4 = idx - b * QPB;
  const float* P = prm + b * PSTRIDE;
  float bfac = P[6], cfac = P[7], sfac = P[8], hfac = P[9];
  bool cj = P[10] != 0.0f;
  bool bl = P[11] != 0.0f;
  size_t base4 = ((size_t)b * NC * PIX) / 4 + p4;
  const float4* in4 = (const float4*)xc;
  float4 r4 = in4[base4];
  float4 g4 = in4[base4 + PIX / 4];
  float4 b4 = in4[base4 + 2 * (PIX / 4)];
  if (cj) {
    float mg = means[b];
    float* rp = (float*)&r4; float* gp = (float*)&g4; float* bp = (float*)&b4;
    #pragma unroll
    for (int k = 0; k < 4; ++k) jitter_px(rp[k], gp[k], bp[k], mg, bfac, cfac, sfac, hfac);
  }
  float4* dst4 = (float4*)(bl ? xj : out);
  dst4[base4] = r4;
  dst4[base4 + PIX / 4] = g4;
  dst4[base4 + 2 * (PIX / 4)] = b4;
}

// ---------------- fused separable gaussian blur (reflect), gated per b -----
__global__ __launch_bounds__(256) void k_blur(const float* __restrict__ xj,
                                              float* __restrict__ out,
                                              const float* __restrict__ prm) {
  int blk = blockIdx.x;
  int tile = blk % NTILE;
  int c = (blk / NTILE) % NC;
  int b = blk / (NTILE * NC);
  const float* P = prm + b * PSTRIDE;
  if (P[11] == 0.0f) return;
  int t = threadIdx.x;
  int oyb = tile * TROWS;

  __shared__ float s_in[TROWS + 14][OS];
  __shared__ float s_mid[TROWS][OS];
  __shared__ float s_k[15];
  if (t < 15) s_k[t] = P[12 + t];

  const float4* plane4 = (const float4*)(xj + (size_t)(b * NC + c) * PIX);
  float* oplane = out + (size_t)(b * NC + c) * PIX;
  {
    float4* s4 = (float4*)&s_in[0][0];
    const int RQ = OS / 4;                       // 56 quads per row
    for (int f = t; f < (TROWS + 14) * RQ; f += 256) {
      int r = f / RQ, col4 = f - r * RQ;
      int yy = oyb - 7 + r;
      yy = (yy < 0) ? -yy : ((yy > OS - 1) ? (2 * (OS - 1) - yy) : yy);
      s4[f] = plane4[yy * RQ + col4];
    }
  }
  __syncthreads();
  if (t < OS) {
    for (int i = 0; i < TROWS; ++i) {
      float acc = 0.0f;
      #pragma unroll
      for (int k = 0; k < 15; ++k) acc += s_k[k] * s_in[i + k][t];
      s_mid[i][t] = acc;
    }
  }
  __syncthreads();
  if (t < OS) {
    for (int i = 0; i < TROWS; ++i) {
      float acc = 0.0f;
      #pragma unroll
      for (int k = 0; k < 15; ++k) {
        int xx = t - 7 + k;
        xx = (xx < 0) ? -xx : ((xx > OS - 1) ? (2 * (OS - 1) - xx) : xx);
        acc += s_k[k] * s_mid[i][xx];
      }
      oplane[(size_t)(oyb + i) * OS + t] = acc;
    }
  }
}

// ---------------- launch ----------------
extern "C" void kernel_launch(void* const* d_in, const int* in_sizes, int n_in,
                              void* d_out, int out_size, void* d_ws, size_t ws_size,
                              hipStream_t stream) {
  const float* x = (const float*)d_in[0];
  float* out = (float*)d_out;
  char* ws = (char*)d_ws;

  float* prm    = (float*)ws;                          // 32768 B
  float* rowsum = (float*)(ws + 32768);                // 43008 B
  float* means  = (float*)(ws + 32768 + 43008);        // 1024 B
  float* bufA   = (float*)(ws + 76800);                // 154140672 B (xj, blur batches)

  k_params<<<1, 256, 0, stream>>>(prm);

  int nblk = NB * NC * NTILE;                          // 10752
  k_resize<<<nblk, 256, 0, stream>>>(x, out, rowsum, prm);   // xc -> d_out
  k_means<<<NB, 64, 0, stream>>>(rowsum, means);

  int nquad = NB * (PIX / 4);                          // 3211264
  k_jitter<<<(nquad + 255) / 256, 256, 0, stream>>>(out, means, prm, bufA, out);

  k_blur<<<nblk, 256, 0, stream>>>(bufA, out, prm);    // blurred b: bufA -> out
}